// Round 3
// baseline (301.611 us; speedup 1.0000x reference)
//
#include <hip/hip_runtime.h>
#include <hip/hip_cooperative_groups.h>
#include <stdint.h>

namespace cg = cooperative_groups;

// ---------------------------------------------------------------------------
// Speaker pairwise loss. R12. History: R10 fused coop (198.7us, launched but
// neutral); R11 added dbuf+counted-vmcnt & unrolled reduce (177.8us) — the
// gain decomposed to the REDUCE fix; the pair dbuf was neutral because the
// binding constraint is occupancy, not load latency: 67KB LDS -> 2 blocks/CU
// -> 8 waves/CU can't hide LDS/MFMA/VALU latency (MFMA busy 14us vs 120us of
// pair time).
// R12: keep dbuf but halve the K-chunk to 32 cols -> LDS 34KB -> 4 blocks/CU
// (VGPR 128 = 4 waves/SIMD cap via __launch_bounds__(256,4), the allocator's
// natural choice under no pressure). Grid NPB=1024 (16 groups/strip, ~2
// off-tiles each) to feed 4 blocks/CU. MFMA K-order unchanged (8 ascending
// K=32 steps) -> pair math bitwise identical. New 32-col bank swizzle
// slot = quad ^ ((row>>1)&3): each 16-lane b128 phase covers all 32 banks
// (2-way = free). Counted vmcnt(4). Reduce gathers 16 rp groups.
// ws: fb bf16[B*D] | rp0/rp1[1024*256] | cp0/cp1[64*33*256] | tmn[B] tmx[B]
// ---------------------------------------------------------------------------

typedef __attribute__((ext_vector_type(8))) short short8;   // 8 bf16
typedef __attribute__((ext_vector_type(4))) float floatx4;  // MFMA C/D

constexpr int D = 256;
constexpr int BM = 128;
constexpr int NT = 64;                    // 8192/128 strips
constexpr int GPS = 16;                   // groups per strip
constexpr int NPB = NT * GPS;             // 1024 pair blocks
constexpr int CPS = 33;                   // cp slots per strip (off 0..32)
constexpr int CW = 32;                    // chunk width (cols)
constexpr int CHK = D / CW;               // 8 chunks per off-tile
constexpr int CHUNK_SH = BM * CW;         // 4096 shorts = 8KB per buffer

__device__ __forceinline__ unsigned f2bf(float f) {  // fp32 -> bf16, RNE
  unsigned u = __float_as_uint(f);
  return (u + 0x7FFFu + ((u >> 16) & 1u)) >> 16;
}

__device__ __forceinline__ void gl_lds16(const void* g, void* l) {
  __builtin_amdgcn_global_load_lds(
      (const __attribute__((address_space(1))) unsigned int*)g,
      (__attribute__((address_space(3))) unsigned int*)l, 16, 0, 0);
}

// ---------------- pair body (32-col dbuf chunks, 4 blocks/CU) ---------------
template <int PASS>
__device__ __forceinline__ void pair_body(
    int bid, const unsigned short* __restrict__ fb, const int* __restrict__ labels,
    const float* __restrict__ tmn, const float* __restrict__ tmx,
    float* __restrict__ rp0, float* __restrict__ rp1,
    float* __restrict__ cp0, float* __restrict__ cp1,
    short* As, short* Bs, int* labA, float* tA0, float* tA1) {
  const int I   = bid >> 4;
  const int g   = bid & 15;
  const int nT  = (I < 32) ? 33 : 32;
  const int t0  = (g * nT) >> 4;
  const int t1  = ((g + 1) * nT) >> 4;
  const int row0 = I * BM;

  const int tid  = threadIdx.x;
  const int lane = tid & 63;
  const int wave = tid >> 6;
  const int l15  = lane & 15;
  const int quad = lane >> 4;
  const int wr   = (wave >> 1) * 64;
  const int wc   = (wave & 1) * 64;

  const float ONE_EPS = 1.0f - 1e-5f;
  const float INF = __builtin_inff();

  __syncthreads();                       // protect smem vs previous phase
  if (tid < BM) {
    labA[tid] = labels[row0 + tid];
    if (PASS == 2) { tA0[tid] = tmn[row0 + tid]; tA1[tid] = tmx[row0 + tid]; }
  }

  // Stage one 32-col chunk (kc) of the A-strip and of column-strip col0 into
  // LDS buffer b. LDS dest is linear (idx*16 = wave-uniform base + lane*16,
  // the gl_lds constraint); the bank swizzle is applied on the GLOBAL source
  // (m173 pattern): LDS 16B-slot sp of row r holds global col-block
  // sp ^ ((r>>1)&3). 4 loads per thread per chunk = 4 vmcnt entries.
  auto stage = [&](int b, int col0, int kc) {
#pragma unroll
    for (int j = 0; j < 2; ++j) {
      int idx = j * 256 + tid;           // 0..511 16B-slots (128 rows x 4)
      int r   = idx >> 2;
      int sp  = idx & 3;
      int cb  = sp ^ ((r >> 1) & 3);     // global col-block held in slot sp
      const char* ga = (const char*)fb + (((size_t)(row0 + r)) << 9) + (kc << 6) + (cb << 4);
      const char* gb = (const char*)fb + (((size_t)(col0 + r)) << 9) + (kc << 6) + (cb << 4);
      gl_lds16(ga, (char*)As + (size_t)b * (CHUNK_SH * 2) + ((size_t)idx << 4));
      gl_lds16(gb, (char*)Bs + (size_t)b * (CHUNK_SH * 2) + ((size_t)idx << 4));
    }
  };

  int arow[4], brow[4];
#pragma unroll
  for (int i = 0; i < 4; ++i) {
    arow[i] = wr + i * 16 + l15;
    brow[i] = wc + i * 16 + l15;
  }

  float s0[16], s1[16];
#pragma unroll
  for (int i = 0; i < 16; ++i) {
    s0[i] = (PASS == 1) ? INF : 0.f;
    s1[i] = (PASS == 1) ? -INF : 0.f;
  }

  // prologue: first off, first chunk into buffer 0
  stage(0, ((I + t0) & 63) * BM, 0);

  int cur = 0;
  for (int off = t0; off < t1; ++off) {
    const int J = (I + off) & 63;
    const int col0 = J * BM;
    const bool diag = (off == 0);

    floatx4 acc[4][4];
#pragma unroll
    for (int rf = 0; rf < 4; ++rf)
#pragma unroll
      for (int cf = 0; cf < 4; ++cf)
        acc[rf][cf] = (floatx4)(0.f);

#pragma unroll
    for (int kc = 0; kc < CHK; ++kc) {
      // prefetch next chunk into the alternate buffer; wait only for the
      // previous chunk's 4 loads (counted vmcnt — never 0 in steady state).
      if (kc < CHK - 1) {
        stage(cur ^ 1, col0, kc + 1);
        asm volatile("s_waitcnt vmcnt(4)" ::: "memory");
      } else if (off + 1 < t1) {
        stage(cur ^ 1, ((I + off + 1) & 63) * BM, 0);
        asm volatile("s_waitcnt vmcnt(4)" ::: "memory");
      } else {
        asm volatile("s_waitcnt vmcnt(0)" ::: "memory");
      }
      __builtin_amdgcn_s_barrier();          // data-ready barrier
      asm volatile("" ::: "memory");

      const short* Ab = As + cur * CHUNK_SH;
      const short* Bb = Bs + cur * CHUNK_SH;
      short8 a[4], b[4];
#pragma unroll
      for (int rf = 0; rf < 4; ++rf)
        a[rf] = *(const short8*)(Ab + arow[rf] * CW + ((quad ^ ((arow[rf] >> 1) & 3)) << 3));
#pragma unroll
      for (int cf = 0; cf < 4; ++cf)
        b[cf] = *(const short8*)(Bb + brow[cf] * CW + ((quad ^ ((brow[cf] >> 1) & 3)) << 3));
#pragma unroll
      for (int rf = 0; rf < 4; ++rf)
#pragma unroll
        for (int cf = 0; cf < 4; ++cf)
          acc[rf][cf] = __builtin_amdgcn_mfma_f32_16x16x32_bf16(a[rf], b[cf], acc[rf][cf], 0, 0, 0);
      asm volatile("s_waitcnt lgkmcnt(0)" ::: "memory");
      __builtin_amdgcn_s_barrier();          // buffer-free barrier
      asm volatile("" ::: "memory");
      cur ^= 1;
    }

    int labc[4];
    float tBn[4], tBx[4];
#pragma unroll
    for (int cf = 0; cf < 4; ++cf) {
      int ci = col0 + wc + cf * 16 + l15;
      labc[cf] = labels[ci];
      if (PASS == 2) { tBn[cf] = tmn[ci]; tBx[cf] = tmx[ci]; }
    }

    float c0[4], c1[4];
#pragma unroll
    for (int i = 0; i < 4; ++i) {
      c0[i] = (PASS == 1) ? INF : 0.f;
      c1[i] = (PASS == 1) ? -INF : 0.f;
    }

#pragma unroll
    for (int rf = 0; rf < 4; ++rf) {
#pragma unroll
      for (int r = 0; r < 4; ++r) {
        const int ri = wr + rf * 16 + quad * 4 + r;
        const int lr = labA[ri];
        float tRn = 0.f, tRx = 0.f;
        if (PASS == 2) { tRn = tA0[ri]; tRx = tA1[ri]; }
#pragma unroll
        for (int cf = 0; cf < 4; ++cf) {
          float sim = acc[rf][cf][r];
          bool same = (lr == labc[cf]);
          bool posok = same && (sim < ONE_EPS);
          if (PASS == 1) {
            float pc = posok ? sim : INF;
            float nc = same ? -INF : sim;
            s0[rf * 4 + r] = fminf(s0[rf * 4 + r], pc);
            s1[rf * 4 + r] = fmaxf(s1[rf * 4 + r], nc);
            c0[cf] = fminf(c0[cf], pc);
            c1[cf] = fmaxf(c1[cf], nc);
          } else {
            if (posok) {
              float e = __expf(fmaf(-2.f, sim, 1.f));
              if (sim < tRx)      s0[rf * 4 + r] += e;
              if (sim < tBx[cf])  c0[cf] += e;
            } else if (!same) {
              float e = (sim > 0.22f) ? __expf(fmaf(50.f, sim, -25.f)) : 0.f;
              if (sim > tRn)      s1[rf * 4 + r] += 1e-30f + e;
              if (sim > tBn[cf])  c1[cf] += 1e-30f + e;
            }
          }
        }
      }
    }

    if (!diag) {
#pragma unroll
      for (int cf = 0; cf < 4; ++cf) {
        float v = c0[cf], w = c1[cf];
#pragma unroll
        for (int m = 16; m < 64; m <<= 1) {
          float vv = __shfl_xor(v, m), ww = __shfl_xor(w, m);
          v = (PASS == 1) ? fminf(v, vv) : (v + vv);
          w = (PASS == 1) ? fmaxf(w, ww) : (w + ww);
        }
        if (quad == 0) {
          size_t o = (size_t)(I * CPS + off) * 256 + (size_t)(wr >> 6) * 128 + wc + cf * 16 + l15;
          cp0[o] = v;
          cp1[o] = w;
        }
      }
    }
  }

#pragma unroll
  for (int i = 0; i < 16; ++i) {
#pragma unroll
    for (int m = 1; m < 16; m <<= 1) {
      float v = __shfl_xor(s0[i], m), w = __shfl_xor(s1[i], m);
      s0[i] = (PASS == 1) ? fminf(s0[i], v) : (s0[i] + v);
      s1[i] = (PASS == 1) ? fmaxf(s1[i], w) : (s1[i] + w);
    }
  }
  if (l15 == 0) {
#pragma unroll
    for (int rf = 0; rf < 4; ++rf)
#pragma unroll
      for (int r = 0; r < 4; ++r) {
        int ri = wr + rf * 16 + quad * 4 + r;
        size_t o = (size_t)bid * 256 + (size_t)(wc >> 6) * 128 + ri;
        rp0[o] = s0[rf * 4 + r];
        rp1[o] = s1[rf * 4 + r];
      }
  }
}

// ---------------- reduce body (unrolled gathers, 16 rp groups) --------------
template <int PASS>
__device__ __forceinline__ void reduce_body(
    int T, const float* __restrict__ rp0, const float* __restrict__ rp1,
    const float* __restrict__ cp0, const float* __restrict__ cp1,
    float* __restrict__ o0, float* __restrict__ o1, float* __restrict__ out,
    float* sA, float* sB, float* sred) {
  const int q = threadIdx.x & 127;
  const int h = threadIdx.x >> 7;

  float a = (PASS == 1) ? __builtin_inff() : 0.f;
  float b = (PASS == 1) ? -__builtin_inff() : 0.f;
#pragma unroll
  for (int g = 0; g < GPS; ++g) {
    size_t o = (size_t)(T * GPS + g) * 256 + (size_t)h * 128 + q;
    float v0 = rp0[o], v1 = rp1[o];
    a = (PASS == 1) ? fminf(a, v0) : (a + v0);
    b = (PASS == 1) ? fmaxf(b, v1) : (b + v1);
  }
  // cp gather by off: I=(T-off)&63; off=1..31 always valid, off=32 iff T>=32.
#pragma unroll
  for (int off = 1; off <= 31; ++off) {
    int Is = (T - off) & 63;
    size_t o = (size_t)(Is * CPS + off) * 256 + (size_t)h * 128 + q;
    float v0 = cp0[o], v1 = cp1[o];
    a = (PASS == 1) ? fminf(a, v0) : (a + v0);
    b = (PASS == 1) ? fmaxf(b, v1) : (b + v1);
  }
  if (T >= 32) {
    int Is = T - 32;
    size_t o = (size_t)(Is * CPS + 32) * 256 + (size_t)h * 128 + q;
    float v0 = cp0[o], v1 = cp1[o];
    a = (PASS == 1) ? fminf(a, v0) : (a + v0);
    b = (PASS == 1) ? fmaxf(b, v1) : (b + v1);
  }
  if (h == 1) { sA[q] = a; sB[q] = b; }
  __syncthreads();
  if (h == 0) {
    a = (PASS == 1) ? fminf(a, sA[q]) : (a + sA[q]);
    b = (PASS == 1) ? fmaxf(b, sB[q]) : (b + sB[q]);
    if (PASS == 1) {
      o0[T * 128 + q] = a - 0.1f;
      o1[T * 128 + q] = b + 0.1f;
    } else {
      float loss = 0.f, cnt = 0.f;
      if (a > 0.f && b > 0.f) {
        loss = 0.5f * log1pf(a) + 0.02f * log1pf(b);
        cnt = 1.f;
      }
#pragma unroll
      for (int m = 1; m < 64; m <<= 1) {
        loss += __shfl_xor(loss, m);
        cnt  += __shfl_xor(cnt, m);
      }
      int wv = threadIdx.x >> 6, ln = threadIdx.x & 63;
      if (ln == 0) { sred[wv] = loss; sred[4 + wv] = cnt; }
    }
  }
  if (PASS == 2) {
    __syncthreads();
    if (threadIdx.x == 0) {
      float L = sred[0] + sred[1];
      float C = sred[4] + sred[5];
      atomicAdd(out, L / 8192.0f);
      atomicAdd(out + 1, -C / 8192.0f);
    }
  }
}

// ---------------- fused cooperative kernel ---------------------------------
// (256, 4): 4 waves/SIMD -> VGPR cap 128 (compiler's natural choice in R11).
// LDS: 2x(As 8K + Bs 8K) = 32KB + ~2KB aux -> 4 blocks/CU (136KB <= 160KB).
// 1024 blocks = 4 x 256 CU co-resident -> coop launch fits exactly.
__global__ __launch_bounds__(256, 4)
void mega_kernel(const float* feats, const int* labels, unsigned short* fb,
                 float* rp0, float* rp1, float* cp0, float* cp1,
                 float* tmn, float* tmx, float* out) {
  __shared__ __align__(16) short As[2 * CHUNK_SH];
  __shared__ __align__(16) short Bs[2 * CHUNK_SH];
  __shared__ int   labA[BM];
  __shared__ float tA0[BM], tA1[BM];

  cg::grid_group grid = cg::this_grid();
  const int bid = blockIdx.x;
  const int tid = threadIdx.x;

  // phase 0: convert fp32 -> bf16 (+ init out)
  const int n4 = 8192 * D / 4;
  for (int i = bid * 256 + tid; i < n4; i += NPB * 256) {
    float4 v = ((const float4*)feats)[i];
    unsigned lo = f2bf(v.x) | (f2bf(v.y) << 16);
    unsigned hi = f2bf(v.z) | (f2bf(v.w) << 16);
    ((uint2*)fb)[i] = make_uint2(lo, hi);
  }
  if (bid == 0 && tid == 0) { out[0] = 0.f; out[1] = 1.f; }
  __threadfence();
  grid.sync();

  // phase 1: pass1
  pair_body<1>(bid, fb, labels, nullptr, nullptr, rp0, rp1, cp0, cp1,
               As, Bs, labA, tA0, tA1);
  __threadfence();
  grid.sync();

  // phase 2: reduce1 -> thresholds
  if (bid < NT)
    reduce_body<1>(bid, rp0, rp1, cp0, cp1, tmn, tmx, out,
                   (float*)As, (float*)As + 128, (float*)As + 256);
  __threadfence();
  grid.sync();

  // phase 3: pass2
  pair_body<2>(bid, fb, labels, tmn, tmx, rp0, rp1, cp0, cp1,
               As, Bs, labA, tA0, tA1);
  __threadfence();
  grid.sync();

  // phase 4: reduce2 + finalize (atomics onto out)
  if (bid < NT)
    reduce_body<2>(bid, rp0, rp1, cp0, cp1, nullptr, nullptr, out,
                   (float*)As, (float*)As + 128, (float*)As + 256);
}

// ---------------- fallback split kernels -----------------------------------
__global__ void convert_kernel(const float* __restrict__ feats,
                               unsigned short* __restrict__ fb, int n4,
                               float* __restrict__ out) {
  int i = blockIdx.x * blockDim.x + threadIdx.x;
  if (i < n4) {
    float4 v = ((const float4*)feats)[i];
    unsigned lo = f2bf(v.x) | (f2bf(v.y) << 16);
    unsigned hi = f2bf(v.z) | (f2bf(v.w) << 16);
    ((uint2*)fb)[i] = make_uint2(lo, hi);
  }
  if (blockIdx.x == 0 && threadIdx.x == 0) { out[0] = 0.f; out[1] = 1.f; }
}

template <int PASS>
__global__ __launch_bounds__(256, 4)
void pair_kernel(const unsigned short* __restrict__ fb, const int* __restrict__ labels,
                 const float* __restrict__ tmn, const float* __restrict__ tmx,
                 float* __restrict__ rp0, float* __restrict__ rp1,
                 float* __restrict__ cp0, float* __restrict__ cp1) {
  __shared__ __align__(16) short As[2 * CHUNK_SH];
  __shared__ __align__(16) short Bs[2 * CHUNK_SH];
  __shared__ int   labA[BM];
  __shared__ float tA0[BM], tA1[BM];
  pair_body<PASS>(blockIdx.x, fb, labels, tmn, tmx, rp0, rp1, cp0, cp1,
                  As, Bs, labA, tA0, tA1);
}

template <int PASS>
__global__ void reduce_kernel(const float* __restrict__ rp0, const float* __restrict__ rp1,
                              const float* __restrict__ cp0, const float* __restrict__ cp1,
                              float* __restrict__ o0, float* __restrict__ o1,
                              float* __restrict__ out) {
  __shared__ float sA[128], sB[128], sred[8];
  reduce_body<PASS>(blockIdx.x, rp0, rp1, cp0, cp1, o0, o1, out, sA, sB, sred);
}

extern "C" void kernel_launch(void* const* d_in, const int* in_sizes, int n_in,
                              void* d_out, int out_size, void* d_ws, size_t ws_size,
                              hipStream_t stream) {
  const float* feats  = (const float*)d_in[0];
  const int*   labels = (const int*)d_in[1];
  const int Bn = in_sizes[1];          // 8192
  float* out = (float*)d_out;

  unsigned short* fb = (unsigned short*)d_ws;                       // 4 MB
  float* rp0 = (float*)((char*)d_ws + (size_t)Bn * D * 2);
  float* rp1 = rp0 + (size_t)NPB * 256;
  float* cp0 = rp1 + (size_t)NPB * 256;
  float* cp1 = cp0 + (size_t)NT * CPS * 256;
  float* tmn = cp1 + (size_t)NT * CPS * 256;
  float* tmx = tmn + Bn;

  bool launched = false;
  int maxb = 0;
  hipError_t qe = hipOccupancyMaxActiveBlocksPerMultiprocessor(
      &maxb, (const void*)mega_kernel, 256, 0);
  if (qe == hipSuccess && maxb * 256 >= NPB) {
    void* args[] = {(void*)&feats, (void*)&labels, (void*)&fb,
                    (void*)&rp0, (void*)&rp1, (void*)&cp0, (void*)&cp1,
                    (void*)&tmn, (void*)&tmx, (void*)&out};
    hipError_t le = hipLaunchCooperativeKernel(
        (const void*)mega_kernel, dim3(NPB), dim3(256), args, 0, stream);
    launched = (le == hipSuccess);
  }
  if (!launched) {
    int n4 = Bn * D / 4;
    convert_kernel<<<(n4 + 255) / 256, 256, 0, stream>>>(feats, fb, n4, out);
    pair_kernel<1><<<NPB, 256, 0, stream>>>(fb, labels, nullptr, nullptr, rp0, rp1, cp0, cp1);
    reduce_kernel<1><<<NT, 256, 0, stream>>>(rp0, rp1, cp0, cp1, tmn, tmx, out);
    pair_kernel<2><<<NPB, 256, 0, stream>>>(fb, labels, tmn, tmx, rp0, rp1, cp0, cp1);
    reduce_kernel<2><<<NT, 256, 0, stream>>>(rp0, rp1, cp0, cp1, nullptr, nullptr, out);
  }
}

// Round 4
// 273.591 us; speedup vs baseline: 1.1024x; 1.1024x over previous
//
#include <hip/hip_runtime.h>
#include <hip/hip_cooperative_groups.h>
#include <stdint.h>

namespace cg = cooperative_groups;

// ---------------------------------------------------------------------------
// Speaker pairwise loss. R13. History: R8 split 199.6us; R10 fused coop
// neutral (198.7); R11 fused + unrolled reduce = 177.8us (gain was the
// reduce fix; pair dbuf neutral); R12 (256,4)+32-col chunks = 301.6us
// REGRESSION — VGPR 64, WRITE_SIZE 343MB => acc[4][4] spilled to scratch.
// Lesson: never bound below the 64-reg accumulator.
// R13 root-causes the pair passes instead: pipes sum to <half of measured
// time with 0 conflicts => lockstep-barrier-bound (8 barriers/off-tile), and
// A was re-staged every chunk despite being invariant across the off loop.
// New structure:
//   * A strip (128x256 bf16, 64KB) staged ONCE per pass into LDS, XOR
//     swizzle slot^(row&7) (same group swizzle R11 measured 0-conflict).
//   * B fragments load DIRECTLY from global (fb is 4MB, L2-resident): the
//     16x16x32 B-fragment is a per-lane contiguous 16B => 1 dwordx4 per
//     fragment; prefetched one K-step ahead (bc/bn, fully unrolled).
//   * Off loop has ZERO barriers / ZERO LDS writes / ZERO vmcnt drains.
//     8 independent waves/CU hide latency without lockstep.
// K-step order (k=0..7 == old kc*2+ks) and all epilogue math unchanged =>
// bitwise-identical results. NPB=512, (256,2) bound (proven VGPR headroom).
// ws: fb bf16[B*D] | rp0/rp1[512*256] | cp0/cp1[64*33*256] | tmn[B] tmx[B]
// ---------------------------------------------------------------------------

typedef __attribute__((ext_vector_type(8))) short short8;   // 8 bf16
typedef __attribute__((ext_vector_type(4))) float floatx4;  // MFMA C/D

constexpr int D = 256;
constexpr int BM = 128;
constexpr int NT = 64;                    // 8192/128 strips
constexpr int GPS = 8;                    // groups per strip
constexpr int NPB = NT * GPS;             // 512 pair blocks
constexpr int CPS = 33;                   // cp slots per strip (off 0..32)
constexpr int ASH = BM * D;               // 32768 shorts = 64KB A tile

__device__ __forceinline__ unsigned f2bf(float f) {  // fp32 -> bf16, RNE
  unsigned u = __float_as_uint(f);
  return (u + 0x7FFFu + ((u >> 16) & 1u)) >> 16;
}

__device__ __forceinline__ void gl_lds16(const void* g, void* l) {
  __builtin_amdgcn_global_load_lds(
      (const __attribute__((address_space(1))) unsigned int*)g,
      (__attribute__((address_space(3))) unsigned int*)l, 16, 0, 0);
}

// ---------------- pair body (A-resident LDS, B from global, no barriers) ----
template <int PASS>
__device__ __forceinline__ void pair_body(
    int bid, const unsigned short* __restrict__ fb, const int* __restrict__ labels,
    const float* __restrict__ tmn, const float* __restrict__ tmx,
    float* __restrict__ rp0, float* __restrict__ rp1,
    float* __restrict__ cp0, float* __restrict__ cp1,
    short* As, int* labA, float* tA0, float* tA1) {
  const int I   = bid >> 3;
  const int g   = bid & 7;
  const int nT  = (I < 32) ? 33 : 32;
  const int t0  = (g * nT) >> 3;
  const int t1  = ((g + 1) * nT) >> 3;
  const int row0 = I * BM;

  const int tid  = threadIdx.x;
  const int lane = tid & 63;
  const int wave = tid >> 6;
  const int l15  = lane & 15;
  const int quad = lane >> 4;
  const int wr   = (wave >> 1) * 64;
  const int wc   = (wave & 1) * 64;

  const float ONE_EPS = 1.0f - 1e-5f;
  const float INF = __builtin_inff();

  __syncthreads();                       // protect LDS vs previous phase
  if (tid < BM) {
    labA[tid] = labels[row0 + tid];
    if (PASS == 2) { tA0[tid] = tmn[row0 + tid]; tA1[tid] = tmx[row0 + tid]; }
  }

  // Stage the full A strip once: 4096 16B-slots, 16 per thread. LDS dest is
  // linear (gl_lds constraint: uniform base + lane*16); bank swizzle applied
  // on the GLOBAL source (m173): slot sl of row r holds col-block sl^(r&7).
#pragma unroll
  for (int j = 0; j < 16; ++j) {
    int idx = j * 256 + tid;             // 0..4095
    int r   = idx >> 5;                  // row 0..127
    int sl  = idx & 31;                  // 16B slot within row
    int cb  = sl ^ (r & 7);              // global col-block held in slot sl
    const char* ga = (const char*)fb + (((size_t)(row0 + r)) << 9) + (cb << 4);
    gl_lds16(ga, (char*)As + ((size_t)idx << 4));
  }
  __syncthreads();                       // A ready; ONLY barrier in the body

  int arow[4], brow[4];
#pragma unroll
  for (int i = 0; i < 4; ++i) {
    arow[i] = wr + i * 16 + l15;
    brow[i] = wc + i * 16 + l15;
  }

  // B fragment loader: one dwordx4 per fragment, straight from global (L2).
  auto loadB = [&](short8 (&b)[4], int c0, int k) {
#pragma unroll
    for (int cf = 0; cf < 4; ++cf) {
      const char* gb = (const char*)fb +
          (((size_t)(c0 + brow[cf])) << 9) + (k << 6) + (quad << 4);
      b[cf] = *(const short8*)gb;
    }
  };

  float s0[16], s1[16];
#pragma unroll
  for (int i = 0; i < 16; ++i) {
    s0[i] = (PASS == 1) ? INF : 0.f;
    s1[i] = (PASS == 1) ? -INF : 0.f;
  }

  short8 bc[4], bn[4];
  loadB(bc, ((I + t0) & 63) * BM, 0);    // prologue: first off, k=0

  for (int off = t0; off < t1; ++off) {
    const int J = (I + off) & 63;
    const int col0 = J * BM;
    const bool diag = (off == 0);
    const int ncol0 = ((I + off + 1) & 63) * BM;
    const bool more = (off + 1 < t1);

    floatx4 acc[4][4];
#pragma unroll
    for (int rf = 0; rf < 4; ++rf)
#pragma unroll
      for (int cf = 0; cf < 4; ++cf)
        acc[rf][cf] = (floatx4)(0.f);

#pragma unroll
    for (int k = 0; k < 8; ++k) {        // K=256 in 8 ascending K=32 steps
      if (k < 7)      loadB(bn, col0, k + 1);
      else if (more)  loadB(bn, ncol0, 0);   // next off-tile's k=0

      short8 a[4];
#pragma unroll
      for (int rf = 0; rf < 4; ++rf) {
        int row = arow[rf];
        int ssl = ((k << 2) + quad) ^ (row & 7);
        a[rf] = *(const short8*)(As + row * D + ssl * 8);
      }
#pragma unroll
      for (int rf = 0; rf < 4; ++rf)
#pragma unroll
        for (int cf = 0; cf < 4; ++cf)
          acc[rf][cf] = __builtin_amdgcn_mfma_f32_16x16x32_bf16(a[rf], bc[cf], acc[rf][cf], 0, 0, 0);
#pragma unroll
      for (int cf = 0; cf < 4; ++cf) bc[cf] = bn[cf];   // SSA rename (unrolled)
    }

    int labc[4];
    float tBn[4], tBx[4];
#pragma unroll
    for (int cf = 0; cf < 4; ++cf) {
      int ci = col0 + wc + cf * 16 + l15;
      labc[cf] = labels[ci];
      if (PASS == 2) { tBn[cf] = tmn[ci]; tBx[cf] = tmx[ci]; }
    }

    float c0[4], c1[4];
#pragma unroll
    for (int i = 0; i < 4; ++i) {
      c0[i] = (PASS == 1) ? INF : 0.f;
      c1[i] = (PASS == 1) ? -INF : 0.f;
    }

#pragma unroll
    for (int rf = 0; rf < 4; ++rf) {
#pragma unroll
      for (int r = 0; r < 4; ++r) {
        const int ri = wr + rf * 16 + quad * 4 + r;
        const int lr = labA[ri];
        float tRn = 0.f, tRx = 0.f;
        if (PASS == 2) { tRn = tA0[ri]; tRx = tA1[ri]; }
#pragma unroll
        for (int cf = 0; cf < 4; ++cf) {
          float sim = acc[rf][cf][r];
          bool same = (lr == labc[cf]);
          bool posok = same && (sim < ONE_EPS);
          if (PASS == 1) {
            float pc = posok ? sim : INF;
            float nc = same ? -INF : sim;
            s0[rf * 4 + r] = fminf(s0[rf * 4 + r], pc);
            s1[rf * 4 + r] = fmaxf(s1[rf * 4 + r], nc);
            c0[cf] = fminf(c0[cf], pc);
            c1[cf] = fmaxf(c1[cf], nc);
          } else {
            if (posok) {
              float e = __expf(fmaf(-2.f, sim, 1.f));
              if (sim < tRx)      s0[rf * 4 + r] += e;
              if (sim < tBx[cf])  c0[cf] += e;
            } else if (!same) {
              float e = (sim > 0.22f) ? __expf(fmaf(50.f, sim, -25.f)) : 0.f;
              if (sim > tRn)      s1[rf * 4 + r] += 1e-30f + e;
              if (sim > tBn[cf])  c1[cf] += 1e-30f + e;
            }
          }
        }
      }
    }

    if (!diag) {
#pragma unroll
      for (int cf = 0; cf < 4; ++cf) {
        float v = c0[cf], w = c1[cf];
#pragma unroll
        for (int m = 16; m < 64; m <<= 1) {
          float vv = __shfl_xor(v, m), ww = __shfl_xor(w, m);
          v = (PASS == 1) ? fminf(v, vv) : (v + vv);
          w = (PASS == 1) ? fmaxf(w, ww) : (w + ww);
        }
        if (quad == 0) {
          size_t o = (size_t)(I * CPS + off) * 256 + (size_t)(wr >> 6) * 128 + wc + cf * 16 + l15;
          cp0[o] = v;
          cp1[o] = w;
        }
      }
    }
  }

#pragma unroll
  for (int i = 0; i < 16; ++i) {
#pragma unroll
    for (int m = 1; m < 16; m <<= 1) {
      float v = __shfl_xor(s0[i], m), w = __shfl_xor(s1[i], m);
      s0[i] = (PASS == 1) ? fminf(s0[i], v) : (s0[i] + v);
      s1[i] = (PASS == 1) ? fmaxf(s1[i], w) : (s1[i] + w);
    }
  }
  if (l15 == 0) {
#pragma unroll
    for (int rf = 0; rf < 4; ++rf)
#pragma unroll
      for (int r = 0; r < 4; ++r) {
        int ri = wr + rf * 16 + quad * 4 + r;
        size_t o = (size_t)bid * 256 + (size_t)(wc >> 6) * 128 + ri;
        rp0[o] = s0[rf * 4 + r];
        rp1[o] = s1[rf * 4 + r];
      }
  }
}

// ---------------- reduce body (R11 unrolled gathers) ------------------------
template <int PASS>
__device__ __forceinline__ void reduce_body(
    int T, const float* __restrict__ rp0, const float* __restrict__ rp1,
    const float* __restrict__ cp0, const float* __restrict__ cp1,
    float* __restrict__ o0, float* __restrict__ o1, float* __restrict__ out,
    float* sA, float* sB, float* sred) {
  const int q = threadIdx.x & 127;
  const int h = threadIdx.x >> 7;

  float a = (PASS == 1) ? __builtin_inff() : 0.f;
  float b = (PASS == 1) ? -__builtin_inff() : 0.f;
#pragma unroll
  for (int g = 0; g < GPS; ++g) {
    size_t o = (size_t)(T * GPS + g) * 256 + (size_t)h * 128 + q;
    float v0 = rp0[o], v1 = rp1[o];
    a = (PASS == 1) ? fminf(a, v0) : (a + v0);
    b = (PASS == 1) ? fmaxf(b, v1) : (b + v1);
  }
  // cp gather by off: I=(T-off)&63; off=1..31 always valid, off=32 iff T>=32.
#pragma unroll
  for (int off = 1; off <= 31; ++off) {
    int Is = (T - off) & 63;
    size_t o = (size_t)(Is * CPS + off) * 256 + (size_t)h * 128 + q;
    float v0 = cp0[o], v1 = cp1[o];
    a = (PASS == 1) ? fminf(a, v0) : (a + v0);
    b = (PASS == 1) ? fmaxf(b, v1) : (b + v1);
  }
  if (T >= 32) {
    int Is = T - 32;
    size_t o = (size_t)(Is * CPS + 32) * 256 + (size_t)h * 128 + q;
    float v0 = cp0[o], v1 = cp1[o];
    a = (PASS == 1) ? fminf(a, v0) : (a + v0);
    b = (PASS == 1) ? fmaxf(b, v1) : (b + v1);
  }
  if (h == 1) { sA[q] = a; sB[q] = b; }
  __syncthreads();
  if (h == 0) {
    a = (PASS == 1) ? fminf(a, sA[q]) : (a + sA[q]);
    b = (PASS == 1) ? fmaxf(b, sB[q]) : (b + sB[q]);
    if (PASS == 1) {
      o0[T * 128 + q] = a - 0.1f;
      o1[T * 128 + q] = b + 0.1f;
    } else {
      float loss = 0.f, cnt = 0.f;
      if (a > 0.f && b > 0.f) {
        loss = 0.5f * log1pf(a) + 0.02f * log1pf(b);
        cnt = 1.f;
      }
#pragma unroll
      for (int m = 1; m < 64; m <<= 1) {
        loss += __shfl_xor(loss, m);
        cnt  += __shfl_xor(cnt, m);
      }
      int wv = threadIdx.x >> 6, ln = threadIdx.x & 63;
      if (ln == 0) { sred[wv] = loss; sred[4 + wv] = cnt; }
    }
  }
  if (PASS == 2) {
    __syncthreads();
    if (threadIdx.x == 0) {
      float L = sred[0] + sred[1];
      float C = sred[4] + sred[5];
      atomicAdd(out, L / 8192.0f);
      atomicAdd(out + 1, -C / 8192.0f);
    }
  }
}

// ---------------- fused cooperative kernel ---------------------------------
// (256, 2): VGPR cap 256 (acc 64 + bc/bn 32 + a 16 + stats 32 + addr ~ fits
// ~170-190, no spill). LDS: As 64KB + aux ~1.5KB -> 2 blocks/CU (131KB<160).
// 512 blocks = 2 x 256 CU co-resident -> coop launch fits.
__global__ __launch_bounds__(256, 2)
void mega_kernel(const float* feats, const int* labels, unsigned short* fb,
                 float* rp0, float* rp1, float* cp0, float* cp1,
                 float* tmn, float* tmx, float* out) {
  __shared__ __align__(16) short As[ASH];
  __shared__ int   labA[BM];
  __shared__ float tA0[BM], tA1[BM];

  cg::grid_group grid = cg::this_grid();
  const int bid = blockIdx.x;
  const int tid = threadIdx.x;

  // phase 0: convert fp32 -> bf16 (+ init out)
  const int n4 = 8192 * D / 4;
  for (int i = bid * 256 + tid; i < n4; i += NPB * 256) {
    float4 v = ((const float4*)feats)[i];
    unsigned lo = f2bf(v.x) | (f2bf(v.y) << 16);
    unsigned hi = f2bf(v.z) | (f2bf(v.w) << 16);
    ((uint2*)fb)[i] = make_uint2(lo, hi);
  }
  if (bid == 0 && tid == 0) { out[0] = 0.f; out[1] = 1.f; }
  __threadfence();
  grid.sync();

  // phase 1: pass1
  pair_body<1>(bid, fb, labels, nullptr, nullptr, rp0, rp1, cp0, cp1,
               As, labA, tA0, tA1);
  __threadfence();
  grid.sync();

  // phase 2: reduce1 -> thresholds
  if (bid < NT)
    reduce_body<1>(bid, rp0, rp1, cp0, cp1, tmn, tmx, out,
                   (float*)As, (float*)As + 128, (float*)As + 256);
  __threadfence();
  grid.sync();

  // phase 3: pass2
  pair_body<2>(bid, fb, labels, tmn, tmx, rp0, rp1, cp0, cp1,
               As, labA, tA0, tA1);
  __threadfence();
  grid.sync();

  // phase 4: reduce2 + finalize (atomics onto out)
  if (bid < NT)
    reduce_body<2>(bid, rp0, rp1, cp0, cp1, nullptr, nullptr, out,
                   (float*)As, (float*)As + 128, (float*)As + 256);
}

// ---------------- fallback split kernels -----------------------------------
__global__ void convert_kernel(const float* __restrict__ feats,
                               unsigned short* __restrict__ fb, int n4,
                               float* __restrict__ out) {
  int i = blockIdx.x * blockDim.x + threadIdx.x;
  if (i < n4) {
    float4 v = ((const float4*)feats)[i];
    unsigned lo = f2bf(v.x) | (f2bf(v.y) << 16);
    unsigned hi = f2bf(v.z) | (f2bf(v.w) << 16);
    ((uint2*)fb)[i] = make_uint2(lo, hi);
  }
  if (blockIdx.x == 0 && threadIdx.x == 0) { out[0] = 0.f; out[1] = 1.f; }
}

template <int PASS>
__global__ __launch_bounds__(256, 2)
void pair_kernel(const unsigned short* __restrict__ fb, const int* __restrict__ labels,
                 const float* __restrict__ tmn, const float* __restrict__ tmx,
                 float* __restrict__ rp0, float* __restrict__ rp1,
                 float* __restrict__ cp0, float* __restrict__ cp1) {
  __shared__ __align__(16) short As[ASH];
  __shared__ int   labA[BM];
  __shared__ float tA0[BM], tA1[BM];
  pair_body<PASS>(blockIdx.x, fb, labels, tmn, tmx, rp0, rp1, cp0, cp1,
                  As, labA, tA0, tA1);
}

template <int PASS>
__global__ void reduce_kernel(const float* __restrict__ rp0, const float* __restrict__ rp1,
                              const float* __restrict__ cp0, const float* __restrict__ cp1,
                              float* __restrict__ o0, float* __restrict__ o1,
                              float* __restrict__ out) {
  __shared__ float sA[128], sB[128], sred[8];
  reduce_body<PASS>(blockIdx.x, rp0, rp1, cp0, cp1, o0, o1, out, sA, sB, sred);
}

extern "C" void kernel_launch(void* const* d_in, const int* in_sizes, int n_in,
                              void* d_out, int out_size, void* d_ws, size_t ws_size,
                              hipStream_t stream) {
  const float* feats  = (const float*)d_in[0];
  const int*   labels = (const int*)d_in[1];
  const int Bn = in_sizes[1];          // 8192
  float* out = (float*)d_out;

  unsigned short* fb = (unsigned short*)d_ws;                       // 4 MB
  float* rp0 = (float*)((char*)d_ws + (size_t)Bn * D * 2);
  float* rp1 = rp0 + (size_t)NPB * 256;
  float* cp0 = rp1 + (size_t)NPB * 256;
  float* cp1 = cp0 + (size_t)NT * CPS * 256;
  float* tmn = cp1 + (size_t)NT * CPS * 256;
  float* tmx = tmn + Bn;

  bool launched = false;
  int maxb = 0;
  hipError_t qe = hipOccupancyMaxActiveBlocksPerMultiprocessor(
      &maxb, (const void*)mega_kernel, 256, 0);
  if (qe == hipSuccess && maxb * 256 >= NPB) {
    void* args[] = {(void*)&feats, (void*)&labels, (void*)&fb,
                    (void*)&rp0, (void*)&rp1, (void*)&cp0, (void*)&cp1,
                    (void*)&tmn, (void*)&tmx, (void*)&out};
    hipError_t le = hipLaunchCooperativeKernel(
        (const void*)mega_kernel, dim3(NPB), dim3(256), args, 0, stream);
    launched = (le == hipSuccess);
  }
  if (!launched) {
    int n4 = Bn * D / 4;
    convert_kernel<<<(n4 + 255) / 256, 256, 0, stream>>>(feats, fb, n4, out);
    pair_kernel<1><<<NPB, 256, 0, stream>>>(fb, labels, nullptr, nullptr, rp0, rp1, cp0, cp1);
    reduce_kernel<1><<<NT, 256, 0, stream>>>(rp0, rp1, cp0, cp1, tmn, tmx, out);
    pair_kernel<2><<<NPB, 256, 0, stream>>>(fb, labels, tmn, tmx, rp0, rp1, cp0, cp1);
    reduce_kernel<2><<<NT, 256, 0, stream>>>(rp0, rp1, cp0, cp1, nullptr, nullptr, out);
  }
}

// Round 5
// 145.012 us; speedup vs baseline: 2.0799x; 1.8867x over previous
//
#include <hip/hip_runtime.h>
#include <hip/hip_cooperative_groups.h>
#include <stdint.h>

namespace cg = cooperative_groups;

// ---------------------------------------------------------------------------
// Speaker pairwise loss. R14. History: R11 fused+unrolled-reduce = 177.8us
// (best). R12 (256,4) spilled acc -> 301us. R13 A-resident/B-global spilled
// arch regs (WRITE 189MB) + L2-missed B (FETCH 403MB) -> 273us.
// Root cause of both: per-wave 64x64 tile needs ~150-190 regs -> only 2
// waves/SIMD -> 8 waves/CU cannot hide latency (pipes sum to <half of pair
// time). R14 shrinks per-wave state instead of scheduling harder:
//   * 512-thread blocks (8 waves), each wave owns 32x64 (acc[2][4]=32,
//     stats 16, operands 24 -> ~110 regs incl AGPR, fits (512,4) cap 128).
//   * LDS unchanged 66KB -> 2 blocks/CU x 8 waves = 16 waves/CU = 4/SIMD,
//     DOUBLE R11's occupancy, no spill.
//   * Inner loop = R11's proven dbuf + counted vmcnt + XOR swizzle,
//     identical K-order -> per-sim values bitwise identical.
//   * rp layout unchanged; cp now 4 row-group partials (x512/slot); reduce
//     spreads rp/cp partials over 4 thread-groups, combines via LDS.
// ws: fb bf16[B*D] | rp0/rp1[512*256] | cp0/cp1[64*33*512] | tmn[B] tmx[B]
// ---------------------------------------------------------------------------

typedef __attribute__((ext_vector_type(8))) short short8;   // 8 bf16
typedef __attribute__((ext_vector_type(4))) float floatx4;  // MFMA C/D

constexpr int D = 256;
constexpr int BM = 128;
constexpr int NT = 64;                    // 8192/128 strips
constexpr int GPS = 8;                    // groups per strip
constexpr int NPB = NT * GPS;             // 512 pair blocks
constexpr int CPS = 33;                   // cp slots per strip (off 0..32)
constexpr int BT = 512;                   // block threads (8 waves)
constexpr int CHUNK_SH = BM * 64;         // 8192 shorts = 16KB per buffer

__device__ __forceinline__ unsigned f2bf(float f) {  // fp32 -> bf16, RNE
  unsigned u = __float_as_uint(f);
  return (u + 0x7FFFu + ((u >> 16) & 1u)) >> 16;
}

__device__ __forceinline__ void gl_lds16(const void* g, void* l) {
  __builtin_amdgcn_global_load_lds(
      (const __attribute__((address_space(1))) unsigned int*)g,
      (__attribute__((address_space(3))) unsigned int*)l, 16, 0, 0);
}

// ---------------- pair body (8 waves, 32x64 per wave, R11 inner loop) -------
template <int PASS>
__device__ __forceinline__ void pair_body(
    int bid, const unsigned short* __restrict__ fb, const int* __restrict__ labels,
    const float* __restrict__ tmn, const float* __restrict__ tmx,
    float* __restrict__ rp0, float* __restrict__ rp1,
    float* __restrict__ cp0, float* __restrict__ cp1,
    short* As, short* Bs, int* labA, float* tA0, float* tA1) {
  const int I   = bid >> 3;
  const int g   = bid & 7;
  const int nT  = (I < 32) ? 33 : 32;
  const int t0  = (g * nT) >> 3;
  const int t1  = ((g + 1) * nT) >> 3;
  const int row0 = I * BM;

  const int tid  = threadIdx.x;
  const int lane = tid & 63;
  const int wave = tid >> 6;               // 0..7
  const int l15  = lane & 15;
  const int quad = lane >> 4;
  const int wr   = (wave >> 1) * 32;       // row offset: 0,32,64,96
  const int wc   = (wave & 1) * 64;        // col offset: 0,64

  const float ONE_EPS = 1.0f - 1e-5f;
  const float INF = __builtin_inff();

  __syncthreads();                       // protect smem vs previous phase
  if (tid < BM) {
    labA[tid] = labels[row0 + tid];
    if (PASS == 2) { tA0[tid] = tmn[row0 + tid]; tA1[tid] = tmx[row0 + tid]; }
  }

  // Stage one 64-col chunk of A-strip + column-strip into LDS buffer b.
  // 1024 16B-slots each; 512 threads -> 2 A + 2 B loads/thread = 4 vmcnt.
  // Linear LDS dest (gl_lds constraint); XOR swizzle on GLOBAL source:
  // slot sl of row r holds global col-block sl^(r&7) (R11-proven, 0 confl).
  auto stage = [&](int b, int col0, int kc) {
#pragma unroll
    for (int j = 0; j < 2; ++j) {
      int idx = j * BT + tid;            // 0..1023
      int r   = idx >> 3;                // row 0..127
      int sl  = idx & 7;                 // 16B slot within 128B row
      int cb  = sl ^ (r & 7);
      const char* ga = (const char*)fb + (((size_t)(row0 + r)) << 9) + (kc << 7) + (cb << 4);
      const char* gb = (const char*)fb + (((size_t)(col0 + r)) << 9) + (kc << 7) + (cb << 4);
      gl_lds16(ga, (char*)As + (size_t)b * (CHUNK_SH * 2) + ((size_t)idx << 4));
      gl_lds16(gb, (char*)Bs + (size_t)b * (CHUNK_SH * 2) + ((size_t)idx << 4));
    }
  };

  int arow[2], brow[4];
#pragma unroll
  for (int i = 0; i < 2; ++i) arow[i] = wr + i * 16 + l15;
#pragma unroll
  for (int i = 0; i < 4; ++i) brow[i] = wc + i * 16 + l15;

  float s0[8], s1[8];
#pragma unroll
  for (int i = 0; i < 8; ++i) {
    s0[i] = (PASS == 1) ? INF : 0.f;
    s1[i] = (PASS == 1) ? -INF : 0.f;
  }

  stage(0, ((I + t0) & 63) * BM, 0);     // prologue

  int cur = 0;
  for (int off = t0; off < t1; ++off) {
    const int J = (I + off) & 63;
    const int col0 = J * BM;
    const bool diag = (off == 0);

    floatx4 acc[2][4];
#pragma unroll
    for (int rf = 0; rf < 2; ++rf)
#pragma unroll
      for (int cf = 0; cf < 4; ++cf)
        acc[rf][cf] = (floatx4)(0.f);

#pragma unroll
    for (int kc = 0; kc < 4; ++kc) {
      if (kc < 3) {
        stage(cur ^ 1, col0, kc + 1);
        asm volatile("s_waitcnt vmcnt(4)" ::: "memory");
      } else if (off + 1 < t1) {
        stage(cur ^ 1, ((I + off + 1) & 63) * BM, 0);
        asm volatile("s_waitcnt vmcnt(4)" ::: "memory");
      } else {
        asm volatile("s_waitcnt vmcnt(0)" ::: "memory");
      }
      __builtin_amdgcn_s_barrier();          // data-ready barrier
      asm volatile("" ::: "memory");

      const short* Ab = As + cur * CHUNK_SH;
      const short* Bb = Bs + cur * CHUNK_SH;
#pragma unroll
      for (int ks = 0; ks < 2; ++ks) {
        const int gg = ks * 4 + quad;
        short8 a[2], b[4];
#pragma unroll
        for (int rf = 0; rf < 2; ++rf)
          a[rf] = *(const short8*)(Ab + arow[rf] * 64 + ((gg ^ (arow[rf] & 7)) << 3));
#pragma unroll
        for (int cf = 0; cf < 4; ++cf)
          b[cf] = *(const short8*)(Bb + brow[cf] * 64 + ((gg ^ (brow[cf] & 7)) << 3));
#pragma unroll
        for (int rf = 0; rf < 2; ++rf)
#pragma unroll
          for (int cf = 0; cf < 4; ++cf)
            acc[rf][cf] = __builtin_amdgcn_mfma_f32_16x16x32_bf16(a[rf], b[cf], acc[rf][cf], 0, 0, 0);
      }
      asm volatile("s_waitcnt lgkmcnt(0)" ::: "memory");
      __builtin_amdgcn_s_barrier();          // buffer-free barrier
      asm volatile("" ::: "memory");
      cur ^= 1;
    }

    int labc[4];
    float tBn[4], tBx[4];
#pragma unroll
    for (int cf = 0; cf < 4; ++cf) {
      int ci = col0 + wc + cf * 16 + l15;
      labc[cf] = labels[ci];
      if (PASS == 2) { tBn[cf] = tmn[ci]; tBx[cf] = tmx[ci]; }
    }

    float c0[4], c1[4];
#pragma unroll
    for (int i = 0; i < 4; ++i) {
      c0[i] = (PASS == 1) ? INF : 0.f;
      c1[i] = (PASS == 1) ? -INF : 0.f;
    }

#pragma unroll
    for (int rf = 0; rf < 2; ++rf) {
#pragma unroll
      for (int r = 0; r < 4; ++r) {
        const int ri = wr + rf * 16 + quad * 4 + r;
        const int lr = labA[ri];
        float tRn = 0.f, tRx = 0.f;
        if (PASS == 2) { tRn = tA0[ri]; tRx = tA1[ri]; }
#pragma unroll
        for (int cf = 0; cf < 4; ++cf) {
          float sim = acc[rf][cf][r];
          bool same = (lr == labc[cf]);
          bool posok = same && (sim < ONE_EPS);
          if (PASS == 1) {
            float pc = posok ? sim : INF;
            float nc = same ? -INF : sim;
            s0[rf * 4 + r] = fminf(s0[rf * 4 + r], pc);
            s1[rf * 4 + r] = fmaxf(s1[rf * 4 + r], nc);
            c0[cf] = fminf(c0[cf], pc);
            c1[cf] = fmaxf(c1[cf], nc);
          } else {
            if (posok) {
              float e = __expf(fmaf(-2.f, sim, 1.f));
              if (sim < tRx)      s0[rf * 4 + r] += e;
              if (sim < tBx[cf])  c0[cf] += e;
            } else if (!same) {
              float e = (sim > 0.22f) ? __expf(fmaf(50.f, sim, -25.f)) : 0.f;
              if (sim > tRn)      s1[rf * 4 + r] += 1e-30f + e;
              if (sim > tBn[cf])  c1[cf] += 1e-30f + e;
            }
          }
        }
      }
    }

    if (!diag) {
#pragma unroll
      for (int cf = 0; cf < 4; ++cf) {
        float v = c0[cf], w = c1[cf];
#pragma unroll
        for (int m = 16; m < 64; m <<= 1) {
          float vv = __shfl_xor(v, m), ww = __shfl_xor(w, m);
          v = (PASS == 1) ? fminf(v, vv) : (v + vv);
          w = (PASS == 1) ? fmaxf(w, ww) : (w + ww);
        }
        if (quad == 0) {
          // 4 row-group partials per (I,off): slot = rowgroup*128 + col
          size_t o = (size_t)(I * CPS + off) * 512 + (size_t)(wr >> 5) * 128 + wc + cf * 16 + l15;
          cp0[o] = v;
          cp1[o] = w;
        }
      }
    }
  }

#pragma unroll
  for (int i = 0; i < 8; ++i) {
#pragma unroll
    for (int m = 1; m < 16; m <<= 1) {
      float v = __shfl_xor(s0[i], m), w = __shfl_xor(s1[i], m);
      s0[i] = (PASS == 1) ? fminf(s0[i], v) : (s0[i] + v);
      s1[i] = (PASS == 1) ? fmaxf(s1[i], w) : (s1[i] + w);
    }
  }
  if (l15 == 0) {
#pragma unroll
    for (int rf = 0; rf < 2; ++rf)
#pragma unroll
      for (int r = 0; r < 4; ++r) {
        int ri = wr + rf * 16 + quad * 4 + r;
        size_t o = (size_t)bid * 256 + (size_t)(wc >> 6) * 128 + ri;
        rp0[o] = s0[rf * 4 + r];
        rp1[o] = s1[rf * 4 + r];
      }
  }
}

// ---------------- reduce body (512 threads, 4 partial groups) ---------------
template <int PASS>
__device__ __forceinline__ void reduce_body(
    int T, const float* __restrict__ rp0, const float* __restrict__ rp1,
    const float* __restrict__ cp0, const float* __restrict__ cp1,
    float* __restrict__ o0, float* __restrict__ o1, float* __restrict__ out,
    float* sA, float* sB, float* sred) {
  const int q  = threadIdx.x & 127;     // row within strip
  const int h4 = threadIdx.x >> 7;      // partial stream 0..3

  float a = (PASS == 1) ? __builtin_inff() : 0.f;
  float b = (PASS == 1) ? -__builtin_inff() : 0.f;
  // rp: 8 groups x 2 col-halves = 16 partials; stream h4 takes 4.
#pragma unroll
  for (int g = 0; g < 4; ++g) {
    int c = h4 * 4 + g;                 // 0..15
    int gg = c >> 1, half = c & 1;
    size_t o = (size_t)(T * GPS + gg) * 256 + (size_t)half * 128 + q;
    float v0 = rp0[o], v1 = rp1[o];
    a = (PASS == 1) ? fminf(a, v0) : (a + v0);
    b = (PASS == 1) ? fmaxf(b, v1) : (b + v1);
  }
  // cp: per off, 4 row-group partials; stream h4 takes rowgroup h4.
#pragma unroll
  for (int off = 1; off <= 31; ++off) {
    int Is = (T - off) & 63;
    size_t o = (size_t)(Is * CPS + off) * 512 + (size_t)h4 * 128 + q;
    float v0 = cp0[o], v1 = cp1[o];
    a = (PASS == 1) ? fminf(a, v0) : (a + v0);
    b = (PASS == 1) ? fmaxf(b, v1) : (b + v1);
  }
  if (T >= 32) {
    int Is = T - 32;
    size_t o = (size_t)(Is * CPS + 32) * 512 + (size_t)h4 * 128 + q;
    float v0 = cp0[o], v1 = cp1[o];
    a = (PASS == 1) ? fminf(a, v0) : (a + v0);
    b = (PASS == 1) ? fmaxf(b, v1) : (b + v1);
  }
  if (h4 > 0) { sA[(h4 - 1) * 128 + q] = a; sB[(h4 - 1) * 128 + q] = b; }
  __syncthreads();
  if (h4 == 0) {
#pragma unroll
    for (int p = 0; p < 3; ++p) {
      float v0 = sA[p * 128 + q], v1 = sB[p * 128 + q];
      a = (PASS == 1) ? fminf(a, v0) : (a + v0);
      b = (PASS == 1) ? fmaxf(b, v1) : (b + v1);
    }
    if (PASS == 1) {
      o0[T * 128 + q] = a - 0.1f;
      o1[T * 128 + q] = b + 0.1f;
    } else {
      float loss = 0.f, cnt = 0.f;
      if (a > 0.f && b > 0.f) {
        loss = 0.5f * log1pf(a) + 0.02f * log1pf(b);
        cnt = 1.f;
      }
#pragma unroll
      for (int m = 1; m < 64; m <<= 1) {
        loss += __shfl_xor(loss, m);
        cnt  += __shfl_xor(cnt, m);
      }
      int wv = threadIdx.x >> 6, ln = threadIdx.x & 63;  // waves 0,1 only
      if (ln == 0) { sred[wv] = loss; sred[4 + wv] = cnt; }
    }
  }
  if (PASS == 2) {
    __syncthreads();
    if (threadIdx.x == 0) {
      float L = sred[0] + sred[1];
      float C = sred[4] + sred[5];
      atomicAdd(out, L / 8192.0f);
      atomicAdd(out + 1, -C / 8192.0f);
    }
  }
}

// ---------------- fused cooperative kernel ---------------------------------
// (512, 4): 4 waves/EU -> 2 blocks/CU (8-wave blocks) -> VGPR cap 128.
// Per-thread state ~110 (acc 32 AGPR + ~80 arch) -> fits, no spill expected.
// LDS: 2x(16K+16K) = 64KB + aux ~2.6KB -> 2 blocks/CU (133KB <= 160KB).
// 512 blocks x 2/CU x 256 CU -> coop launch fits.
__global__ __launch_bounds__(BT, 4)
void mega_kernel(const float* feats, const int* labels, unsigned short* fb,
                 float* rp0, float* rp1, float* cp0, float* cp1,
                 float* tmn, float* tmx, float* out) {
  __shared__ __align__(16) short As[2 * CHUNK_SH];
  __shared__ __align__(16) short Bs[2 * CHUNK_SH];
  __shared__ int   labA[BM];
  __shared__ float tA0[BM], tA1[BM];

  cg::grid_group grid = cg::this_grid();
  const int bid = blockIdx.x;
  const int tid = threadIdx.x;

  // phase 0: convert fp32 -> bf16 (+ init out)
  const int n4 = 8192 * D / 4;
  for (int i = bid * BT + tid; i < n4; i += NPB * BT) {
    float4 v = ((const float4*)feats)[i];
    unsigned lo = f2bf(v.x) | (f2bf(v.y) << 16);
    unsigned hi = f2bf(v.z) | (f2bf(v.w) << 16);
    ((uint2*)fb)[i] = make_uint2(lo, hi);
  }
  if (bid == 0 && tid == 0) { out[0] = 0.f; out[1] = 1.f; }
  __threadfence();
  grid.sync();

  // phase 1: pass1
  pair_body<1>(bid, fb, labels, nullptr, nullptr, rp0, rp1, cp0, cp1,
               As, Bs, labA, tA0, tA1);
  __threadfence();
  grid.sync();

  // phase 2: reduce1 -> thresholds
  if (bid < NT)
    reduce_body<1>(bid, rp0, rp1, cp0, cp1, tmn, tmx, out,
                   (float*)As, (float*)As + 384, (float*)As + 768);
  __threadfence();
  grid.sync();

  // phase 3: pass2
  pair_body<2>(bid, fb, labels, tmn, tmx, rp0, rp1, cp0, cp1,
               As, Bs, labA, tA0, tA1);
  __threadfence();
  grid.sync();

  // phase 4: reduce2 + finalize (atomics onto out)
  if (bid < NT)
    reduce_body<2>(bid, rp0, rp1, cp0, cp1, nullptr, nullptr, out,
                   (float*)As, (float*)As + 384, (float*)As + 768);
}

// ---------------- fallback split kernels -----------------------------------
__global__ void convert_kernel(const float* __restrict__ feats,
                               unsigned short* __restrict__ fb, int n4,
                               float* __restrict__ out) {
  int i = blockIdx.x * blockDim.x + threadIdx.x;
  if (i < n4) {
    float4 v = ((const float4*)feats)[i];
    unsigned lo = f2bf(v.x) | (f2bf(v.y) << 16);
    unsigned hi = f2bf(v.z) | (f2bf(v.w) << 16);
    ((uint2*)fb)[i] = make_uint2(lo, hi);
  }
  if (blockIdx.x == 0 && threadIdx.x == 0) { out[0] = 0.f; out[1] = 1.f; }
}

template <int PASS>
__global__ __launch_bounds__(BT, 4)
void pair_kernel(const unsigned short* __restrict__ fb, const int* __restrict__ labels,
                 const float* __restrict__ tmn, const float* __restrict__ tmx,
                 float* __restrict__ rp0, float* __restrict__ rp1,
                 float* __restrict__ cp0, float* __restrict__ cp1) {
  __shared__ __align__(16) short As[2 * CHUNK_SH];
  __shared__ __align__(16) short Bs[2 * CHUNK_SH];
  __shared__ int   labA[BM];
  __shared__ float tA0[BM], tA1[BM];
  pair_body<PASS>(blockIdx.x, fb, labels, tmn, tmx, rp0, rp1, cp0, cp1,
                  As, Bs, labA, tA0, tA1);
}

template <int PASS>
__global__ void reduce_kernel(const float* __restrict__ rp0, const float* __restrict__ rp1,
                              const float* __restrict__ cp0, const float* __restrict__ cp1,
                              float* __restrict__ o0, float* __restrict__ o1,
                              float* __restrict__ out) {
  __shared__ float sA[384], sB[384], sred[8];
  reduce_body<PASS>(blockIdx.x, rp0, rp1, cp0, cp1, o0, o1, out, sA, sB, sred);
}

extern "C" void kernel_launch(void* const* d_in, const int* in_sizes, int n_in,
                              void* d_out, int out_size, void* d_ws, size_t ws_size,
                              hipStream_t stream) {
  const float* feats  = (const float*)d_in[0];
  const int*   labels = (const int*)d_in[1];
  const int Bn = in_sizes[1];          // 8192
  float* out = (float*)d_out;

  unsigned short* fb = (unsigned short*)d_ws;                       // 4 MB
  float* rp0 = (float*)((char*)d_ws + (size_t)Bn * D * 2);
  float* rp1 = rp0 + (size_t)NPB * 256;
  float* cp0 = rp1 + (size_t)NPB * 256;
  float* cp1 = cp0 + (size_t)NT * CPS * 512;
  float* tmn = cp1 + (size_t)NT * CPS * 512;
  float* tmx = tmn + Bn;

  bool launched = false;
  int maxb = 0;
  hipError_t qe = hipOccupancyMaxActiveBlocksPerMultiprocessor(
      &maxb, (const void*)mega_kernel, BT, 0);
  if (qe == hipSuccess && maxb * 256 >= NPB) {
    void* args[] = {(void*)&feats, (void*)&labels, (void*)&fb,
                    (void*)&rp0, (void*)&rp1, (void*)&cp0, (void*)&cp1,
                    (void*)&tmn, (void*)&tmx, (void*)&out};
    hipError_t le = hipLaunchCooperativeKernel(
        (const void*)mega_kernel, dim3(NPB), dim3(BT), args, 0, stream);
    launched = (le == hipSuccess);
  }
  if (!launched) {
    int n4 = Bn * D / 4;
    convert_kernel<<<(n4 + 255) / 256, 256, 0, stream>>>(feats, fb, n4, out);
    pair_kernel<1><<<NPB, BT, 0, stream>>>(fb, labels, nullptr, nullptr, rp0, rp1, cp0, cp1);
    reduce_kernel<1><<<NT, BT, 0, stream>>>(rp0, rp1, cp0, cp1, tmn, tmx, out);
    pair_kernel<2><<<NPB, BT, 0, stream>>>(fb, labels, tmn, tmx, rp0, rp1, cp0, cp1);
    reduce_kernel<2><<<NT, BT, 0, stream>>>(rp0, rp1, cp0, cp1, nullptr, nullptr, out);
  }
}